// Round 2
// baseline (542.275 us; speedup 1.0000x reference)
//
#include <hip/hip_runtime.h>
#include <math.h>

#define BATCH 128
#define NINS  4096
#define NHID  128
#define KH    64
#define NPART 64                   // one 64-n tile per wave -> 64 partials per batch
#define PART_STRIDE (NHID + 2)     // m, L, out[128]

// --------------------------------------------------------------------------
// Kernel A: c[b][k] = b1[k] + sum_d inputs[b,index,d] * W1[d][k]
// (the "own" half of the first linear layer, constant across n per batch)
// --------------------------------------------------------------------------
__global__ void precompute_c(const float* __restrict__ inputs,
                             const int* __restrict__ index_p,
                             const float* __restrict__ W1,
                             const float* __restrict__ b1,
                             float* __restrict__ c) {
    const int b = blockIdx.x;
    const int k = threadIdx.x;   // 0..63
    const int idx = index_p[0];
    const float* own = inputs + ((size_t)b * NINS + idx) * NHID;
    float acc = b1[k];
    #pragma unroll 8
    for (int d = 0; d < NHID; ++d)
        acc = fmaf(own[d], W1[d * KH + k], acc);   // W1[d*64+k]: coalesced
    c[b * KH + k] = acc;
}

// --------------------------------------------------------------------------
// Kernel B: main pass. 4 waves per block, one 64-n tile per wave.
// lane = n within tile. h[k] accumulators in VGPRs, W1 rows via scalar
// loads (wave-uniform). Per-wave softmax partial (m, L, out[128]).
// --------------------------------------------------------------------------
__global__ __launch_bounds__(256)
void att_partial(const float* __restrict__ inputs,
                 const float* __restrict__ W1,
                 const float* __restrict__ W2,
                 const float* __restrict__ b2_p,
                 const float* __restrict__ c,
                 float* __restrict__ part) {
    const int lane = threadIdx.x & 63;
    const int wv   = threadIdx.x >> 6;            // 0..3
    const int tile = blockIdx.x * 4 + wv;         // 0..63
    const int b    = blockIdx.y;
    const int n0   = tile * 64;

    const float* Wb    = W1 + (size_t)NHID * KH;  // bottom rows d=128..255
    const float* xbase = inputs + (size_t)b * NINS * NHID;
    const float* xrow  = xbase + (size_t)(n0 + lane) * NHID;
    const float* cb    = c + b * KH;

    float h[KH];
    #pragma unroll
    for (int k = 0; k < KH; ++k) h[k] = cb[k];    // uniform -> s_load

    // GEMM: h[k] += x[d] * Wb[d][k], d-chunks of 16 (keep regs tight)
    for (int dc = 0; dc < NHID; dc += 16) {
        float4 xv[4];
        #pragma unroll
        for (int i = 0; i < 4; ++i)
            xv[i] = *(const float4*)(xrow + dc + i * 4);
        const float* xs = (const float*)xv;
        #pragma unroll
        for (int i = 0; i < 16; ++i) {
            const float xd = xs[i];
            const float* wrow = Wb + (size_t)(dc + i) * KH;  // uniform row
            #pragma unroll
            for (int k = 0; k < KH; ++k)
                h[k] = fmaf(xd, wrow[k], h[k]);   // v_fmac v,s,v
        }
    }

    // att = b2 + sum_k relu(h[k]) * W2[k]
    float att = b2_p[0];
    #pragma unroll
    for (int k = 0; k < KH; ++k)
        att = fmaf(fmaxf(h[k], 0.0f), W2[k], att);

    // wave max
    float m = att;
    #pragma unroll
    for (int off = 32; off; off >>= 1)
        m = fmaxf(m, __shfl_xor(m, off));

    const float e = __expf(att - m);
    float L = e;
    #pragma unroll
    for (int off = 32; off; off >>= 1)
        L += __shfl_xor(L, off);

    // weighted sum over this tile: lane j accumulates d=j and d=j+64.
    // Unrolled x8 with batched shfl+loads so VMEM/LDS latency is amortized.
    float o0 = 0.0f, o1 = 0.0f;
    const float* xt = xbase + (size_t)n0 * NHID + lane;
    #pragma unroll
    for (int lb = 0; lb < 64; lb += 8) {
        float ev[8], xa[8], xb[8];
        #pragma unroll
        for (int j = 0; j < 8; ++j) {
            ev[j] = __shfl(e, lb + j);
            xa[j] = xt[(size_t)(lb + j) * NHID];
            xb[j] = xt[(size_t)(lb + j) * NHID + 64];
        }
        #pragma unroll
        for (int j = 0; j < 8; ++j) {
            o0 = fmaf(ev[j], xa[j], o0);
            o1 = fmaf(ev[j], xb[j], o1);
        }
    }

    float* p = part + (size_t)(b * NPART + tile) * PART_STRIDE;
    if (lane == 0) { p[0] = m; p[1] = L; }
    p[2 + lane]      = o0;
    p[2 + lane + 64] = o1;
}

// --------------------------------------------------------------------------
// Kernel C: merge 64 partials per batch -> out[b][d]
// --------------------------------------------------------------------------
__global__ void finalize(const float* __restrict__ part,
                         float* __restrict__ out) {
    const int b = blockIdx.x;
    const int d = threadIdx.x;   // 0..127
    const float* pb = part + (size_t)b * NPART * PART_STRIDE;

    float M = -INFINITY;
    #pragma unroll 8
    for (int p = 0; p < NPART; ++p)
        M = fmaxf(M, pb[p * PART_STRIDE]);

    float S = 0.0f, acc = 0.0f;
    #pragma unroll 4
    for (int p = 0; p < NPART; ++p) {
        const float sc = __expf(pb[p * PART_STRIDE] - M);
        S   = fmaf(sc, pb[p * PART_STRIDE + 1], S);
        acc = fmaf(sc, pb[p * PART_STRIDE + 2 + d], acc);
    }
    out[b * NHID + d] = acc / S;
}

// --------------------------------------------------------------------------
extern "C" void kernel_launch(void* const* d_in, const int* in_sizes, int n_in,
                              void* d_out, int out_size, void* d_ws, size_t ws_size,
                              hipStream_t stream) {
    const float* inputs = (const float*)d_in[0];
    const int*   index  = (const int*)  d_in[1];
    // d_in[2] = claims (unused by forward)
    const float* W1     = (const float*)d_in[3];
    const float* b1     = (const float*)d_in[4];
    const float* W2     = (const float*)d_in[5];
    const float* b2     = (const float*)d_in[6];
    float* out = (float*)d_out;

    float* c    = (float*)d_ws;                 // BATCH*KH floats = 32 KB
    float* part = c + BATCH * KH;               // BATCH*64*130 floats ~= 4.3 MB

    precompute_c<<<dim3(BATCH), dim3(64), 0, stream>>>(inputs, index, W1, b1, c);

    dim3 gB(NPART / 4, BATCH);                  // 16 x 128 blocks, 4 waves each
    att_partial<<<gB, dim3(256), 0, stream>>>(inputs, W1, W2, b2, c, part);

    finalize<<<dim3(BATCH), dim3(NHID), 0, stream>>>(part, out);
}

// Round 3
// 440.990 us; speedup vs baseline: 1.2297x; 1.2297x over previous
//
#include <hip/hip_runtime.h>
#include <math.h>

#define BATCH 128
#define NINS  4096
#define NHID  128
#define KH    64
#define NPART 64                    // 64 tiles of 64 n per batch
#define PART_STRIDE 136             // [0]=m, [1]=L, [8..135]=o[128]; 16B-aligned
#define O_OFF 8
#define TILES_PER_WAVE 4

typedef __attribute__((ext_vector_type(8))) short short8;   // 8 x bf16
typedef __attribute__((ext_vector_type(4))) float f32x4;

__device__ inline unsigned short f2bf(float f) {
    union { float f; unsigned u; } v; v.f = f;
    return (unsigned short)((v.u + 0x7FFFu + ((v.u >> 16) & 1u)) >> 16);
}

// --------------------------------------------------------------------------
// Kernel A: c[b][k] = b1[k] + sum_d inputs[b,index,d] * W1[d][k]  (fp32 exact)
// --------------------------------------------------------------------------
__global__ void precompute_c(const float* __restrict__ inputs,
                             const int* __restrict__ index_p,
                             const float* __restrict__ W1,
                             const float* __restrict__ b1,
                             float* __restrict__ c) {
    const int b = blockIdx.x;
    const int k = threadIdx.x;   // 0..63
    const int idx = index_p[0];
    const float* own = inputs + ((size_t)b * NINS + idx) * NHID;
    float acc = b1[k];
    #pragma unroll 8
    for (int d = 0; d < NHID; ++d)
        acc = fmaf(own[d], W1[d * KH + k], acc);
    c[b * KH + k] = acc;
}

// --------------------------------------------------------------------------
// Kernel B: MFMA main pass. 4 waves/block, 4 tiles/wave, tile = 64n x 64k.
// h = x(bf16) @ Wb(bf16) + c  via 16x16x32 bf16 MFMA (fp32 accumulate).
// A-frags loaded straight from global (A[m=lane&15][k=quad*8+j]);
// all 16 B-frags of Wb resident in regs.
// --------------------------------------------------------------------------
__global__ __launch_bounds__(256)
void att_partial(const float* __restrict__ inputs,
                 const float* __restrict__ W1,
                 const float* __restrict__ W2,
                 const float* __restrict__ b2_p,
                 const float* __restrict__ c,
                 float* __restrict__ part) {
    __shared__ float ebuf[4][64];
    const int lane = threadIdx.x & 63;
    const int wv   = threadIdx.x >> 6;
    const int b    = blockIdx.y;
    const int quad = lane >> 4;
    const int m16  = lane & 15;

    const float* Wb = W1 + (size_t)NHID * KH;             // rows d=128..255
    const float* xb = inputs + (size_t)b * NINS * NHID;

    // ---- B fragments (whole Wb), loaded once: Bf[ks][nf] ----
    short8 Bf[4][4];
    #pragma unroll
    for (int ks = 0; ks < 4; ++ks)
        #pragma unroll
        for (int nf = 0; nf < 4; ++nf) {
            const float* wp = Wb + (size_t)(ks * 32 + quad * 8) * KH + nf * 16 + m16;
            short8 f;
            #pragma unroll
            for (int j = 0; j < 8; ++j) f[j] = (short)f2bf(wp[(size_t)j * KH]);
            Bf[ks][nf] = f;
        }

    float w2v[4];
    #pragma unroll
    for (int nf = 0; nf < 4; ++nf) w2v[nf] = W2[nf * 16 + m16];
    const float b2v = b2_p[0];
    float cv[4];
    #pragma unroll
    for (int nf = 0; nf < 4; ++nf) cv[nf] = c[b * KH + nf * 16 + m16];

    for (int t = 0; t < TILES_PER_WAVE; ++t) {
        const int tile = (blockIdx.x * 4 + wv) * TILES_PER_WAVE + t;
        const int n0   = tile * 64;

        f32x4 acc[4][4];
        #pragma unroll
        for (int mf = 0; mf < 4; ++mf)
            #pragma unroll
            for (int nf = 0; nf < 4; ++nf) {
                f32x4 z = {cv[nf], cv[nf], cv[nf], cv[nf]};
                acc[mf][nf] = z;
            }

        #pragma unroll
        for (int ks = 0; ks < 4; ++ks) {
            short8 Af[4];
            #pragma unroll
            for (int mf = 0; mf < 4; ++mf) {
                const float* row = xb + (size_t)(n0 + mf * 16 + m16) * NHID
                                      + ks * 32 + quad * 8;
                f32x4 a = *(const f32x4*)row;
                f32x4 bq = *(const f32x4*)(row + 4);
                short8 f;
                f[0] = (short)f2bf(a.x);  f[1] = (short)f2bf(a.y);
                f[2] = (short)f2bf(a.z);  f[3] = (short)f2bf(a.w);
                f[4] = (short)f2bf(bq.x); f[5] = (short)f2bf(bq.y);
                f[6] = (short)f2bf(bq.z); f[7] = (short)f2bf(bq.w);
                Af[mf] = f;
            }
            #pragma unroll
            for (int mf = 0; mf < 4; ++mf)
                #pragma unroll
                for (int nf = 0; nf < 4; ++nf)
                    acc[mf][nf] = __builtin_amdgcn_mfma_f32_16x16x32_bf16(
                        Af[mf], Bf[ks][nf], acc[mf][nf], 0, 0, 0);
        }

        // ---- epilogue: att[n] = b2 + sum_k relu(h[n][k]) * W2[k] ----
        // C layout: row(n) = quad*4 + r, col(k) = nf*16 + m16
        float att[4][4];   // [mf][r]
        #pragma unroll
        for (int mf = 0; mf < 4; ++mf)
            #pragma unroll
            for (int r = 0; r < 4; ++r) {
                float s = 0.0f;
                #pragma unroll
                for (int nf = 0; nf < 4; ++nf)
                    s = fmaf(fmaxf(acc[mf][nf][r], 0.0f), w2v[nf], s);
                s += __shfl_xor(s, 1);
                s += __shfl_xor(s, 2);
                s += __shfl_xor(s, 4);
                s += __shfl_xor(s, 8);
                att[mf][r] = s + b2v;
            }

        // wave max / exp / sum  (each lane's 16 att's partition n by quad)
        float mx = att[0][0];
        #pragma unroll
        for (int mf = 0; mf < 4; ++mf)
            #pragma unroll
            for (int r = 0; r < 4; ++r) mx = fmaxf(mx, att[mf][r]);
        mx = fmaxf(mx, __shfl_xor(mx, 16));
        mx = fmaxf(mx, __shfl_xor(mx, 32));

        float ev[4][4];
        float L = 0.0f;
        #pragma unroll
        for (int mf = 0; mf < 4; ++mf)
            #pragma unroll
            for (int r = 0; r < 4; ++r) {
                ev[mf][r] = __expf(att[mf][r] - mx);
                L += ev[mf][r];
            }
        L += __shfl_xor(L, 16);
        L += __shfl_xor(L, 32);

        // stage e[64] in per-wave LDS (one writer lane per quad-group)
        if (m16 == 0) {
            #pragma unroll
            for (int mf = 0; mf < 4; ++mf)
                #pragma unroll
                for (int r = 0; r < 4; ++r)
                    ebuf[wv][mf * 16 + quad * 4 + r] = ev[mf][r];
        }
        // same-wave DS ordering; compiler inserts lgkmcnt wait before reads

        // ---- weighted sum: o[d] = sum_n e_n * x[n][d] ----
        const int G  = lane >> 5;            // n-half
        const int db = (lane & 31) * 4;      // d-base (float4)
        f32x4 o = {0.0f, 0.0f, 0.0f, 0.0f};
        #pragma unroll
        for (int nn = 0; nn < 32; nn += 8) {
            f32x4 e4a = *(const f32x4*)&ebuf[wv][G * 32 + nn];
            f32x4 e4b = *(const f32x4*)&ebuf[wv][G * 32 + nn + 4];
            const float* xrow0 = xb + (size_t)(n0 + G * 32 + nn) * NHID + db;
            #pragma unroll
            for (int j = 0; j < 4; ++j) {
                f32x4 xv = *(const f32x4*)(xrow0 + (size_t)j * NHID);
                o += xv * e4a[j];
            }
            #pragma unroll
            for (int j = 0; j < 4; ++j) {
                f32x4 xv = *(const f32x4*)(xrow0 + (size_t)(j + 4) * NHID);
                o += xv * e4b[j];
            }
        }
        #pragma unroll
        for (int i = 0; i < 4; ++i) o[i] += __shfl_xor(o[i], 32);

        float* p = part + (size_t)(b * NPART + tile) * PART_STRIDE;
        if (lane == 0) { p[0] = mx; p[1] = L; }
        if (lane < 32) *(f32x4*)(p + O_OFF + db) = o;
    }
}

// --------------------------------------------------------------------------
// Kernel C: merge 64 partials per batch -> out[b][d]
// --------------------------------------------------------------------------
__global__ void finalize(const float* __restrict__ part,
                         float* __restrict__ out) {
    const int b = blockIdx.x;
    const int d = threadIdx.x;   // 0..127
    const float* pb = part + (size_t)b * NPART * PART_STRIDE;

    float M = pb[0];
    #pragma unroll 8
    for (int p = 1; p < NPART; ++p)
        M = fmaxf(M, pb[p * PART_STRIDE]);

    float S = 0.0f, acc = 0.0f;
    #pragma unroll 4
    for (int p = 0; p < NPART; ++p) {
        const float sc = __expf(pb[p * PART_STRIDE] - M);
        S   = fmaf(sc, pb[p * PART_STRIDE + 1], S);
        acc = fmaf(sc, pb[p * PART_STRIDE + O_OFF + d], acc);
    }
    out[b * NHID + d] = acc / S;
}

// --------------------------------------------------------------------------
extern "C" void kernel_launch(void* const* d_in, const int* in_sizes, int n_in,
                              void* d_out, int out_size, void* d_ws, size_t ws_size,
                              hipStream_t stream) {
    const float* inputs = (const float*)d_in[0];
    const int*   index  = (const int*)  d_in[1];
    // d_in[2] = claims (unused by forward)
    const float* W1     = (const float*)d_in[3];
    const float* b1     = (const float*)d_in[4];
    const float* W2     = (const float*)d_in[5];
    const float* b2     = (const float*)d_in[6];
    float* out = (float*)d_out;

    float* c    = (float*)d_ws;                 // 128*64 floats = 32 KB
    float* part = c + BATCH * KH;               // 128*64*136 floats ~= 4.25 MB

    precompute_c<<<dim3(BATCH), dim3(64), 0, stream>>>(inputs, index, W1, b1, c);

    dim3 gB(4, BATCH);                          // 512 blocks x 4 waves, 4 tiles/wave
    att_partial<<<gB, dim3(256), 0, stream>>>(inputs, W1, W2, b2, c, part);

    finalize<<<dim3(BATCH), dim3(NHID), 0, stream>>>(part, out);
}